// Round 1
// baseline (1808.476 us; speedup 1.0000x reference)
//
#include <hip/hip_runtime.h>

#define H 0.1f

typedef float float4v __attribute__((ext_vector_type(4)));

__device__ __forceinline__ float bcast_lane(float v, int l) {
    return __int_as_float(__builtin_amdgcn_readlane(__float_as_int(v), l));
}

// ---------------- init: X0 = relu(W*(key_emb[x0]+val_emb[x1]) + b) ----------
__global__ void __launch_bounds__(256) init_kernel(
    const int* __restrict__ xnode, const float* __restrict__ key_emb,
    const float* __restrict__ val_emb, const float* __restrict__ lw,
    const float* __restrict__ lb, float* __restrict__ X0, int n)
{
    int lane = threadIdx.x & 63;
    int v = (blockIdx.x * blockDim.x + threadIdx.x) >> 6;
    if (v >= n) return;
    int k0 = xnode[2 * v + 0], k1 = xnode[2 * v + 1];
    float e = key_emb[k0 * 64 + lane] + val_emb[k1 * 64 + lane];
    float wrow[64];
    const float* wp = lw + (size_t)lane * 64;
#pragma unroll
    for (int q = 0; q < 16; ++q) {
        float4v w = *(const float4v*)(wp + 4 * q);
        wrow[4 * q + 0] = w[0]; wrow[4 * q + 1] = w[1];
        wrow[4 * q + 2] = w[2]; wrow[4 * q + 3] = w[3];
    }
    float acc = lb[lane];
#pragma unroll
    for (int d = 0; d < 64; ++d)
        acc = fmaf(bcast_lane(e, d), wrow[d], acc);
    X0[(size_t)v * 64 + lane] = acc > 0.f ? acc : 0.f;
}

// ---------------- CSR build ----------------
__global__ void __launch_bounds__(256) count_kernel(
    const int* __restrict__ col, int* __restrict__ cnt, int E)
{
    int e = blockIdx.x * blockDim.x + threadIdx.x;
    if (e < E) atomicAdd(&cnt[col[e]], 1);
}

__global__ void __launch_bounds__(1024) scan_kernel(
    const int* __restrict__ cnt, int* __restrict__ ptr,
    int* __restrict__ fillpos, int n)
{
    __shared__ int wsum[16];
    __shared__ int carry_s;
    int tid = threadIdx.x, lane = tid & 63, wid = tid >> 6;
    if (tid == 0) carry_s = 0;
    __syncthreads();
    for (int base = 0; base < n; base += 1024) {
        int i = base + tid;
        int v = (i < n) ? cnt[i] : 0;
        int s = v;
#pragma unroll
        for (int off = 1; off < 64; off <<= 1) {
            int t = __shfl_up(s, off);
            if (lane >= off) s += t;
        }
        if (lane == 63) wsum[wid] = s;
        __syncthreads();
        if (tid < 16) {
            int ws = wsum[tid];
#pragma unroll
            for (int off = 1; off < 16; off <<= 1) {
                int t = __shfl_up(ws, off);
                if (tid >= off) ws += t;
            }
            wsum[tid] = ws;
        }
        __syncthreads();
        int carry = carry_s;
        int wbase = (wid == 0) ? 0 : wsum[wid - 1];
        int excl = carry + wbase + (s - v);
        if (i < n) { ptr[i] = excl; fillpos[i] = excl; }
        __syncthreads();
        if (tid == 0) carry_s = carry + wsum[15];
        __syncthreads();
    }
    if (threadIdx.x == 0) ptr[n] = carry_s;
}

__global__ void __launch_bounds__(256) fill_kernel(
    const int* __restrict__ row, const int* __restrict__ col,
    int* __restrict__ fillpos, int* __restrict__ csr, int E)
{
    int e = blockIdx.x * blockDim.x + threadIdx.x;
    if (e < E) {
        int p = atomicAdd(&fillpos[col[e]], 1);
        csr[p] = row[e];
    }
}

// ---------------- one time step: wave layer + 4 oscillator layers -----------
__global__ void __launch_bounds__(256) step_kernel(
    const float* __restrict__ Xin, float* __restrict__ Xout,
    float* __restrict__ Y, float* __restrict__ Z, float* __restrict__ U,
    const int* __restrict__ ptr, const int* __restrict__ csr,
    const float* __restrict__ osc_a, const float* __restrict__ Bw,
    const float* __restrict__ Bb, int n, int nper)
{
    const int lane = threadIdx.x & 63;
    const int gw = (blockIdx.x * blockDim.x + threadIdx.x) >> 6;
    const int v0 = gw * nper;
    if (v0 >= n) return;
    const int v1 = (v0 + nper < n) ? (v0 + nper) : n;
    const size_t nd = (size_t)n * 64;

    // ---- phase 0: wave layer (graph Laplacian leapfrog), X ping-pong ----
    for (int v = v0; v < v1; ++v) {
        float x = Xin[(size_t)v * 64 + lane];
        float y = Y[(size_t)v * 64 + lane];
        int b = ptr[v], e = ptr[v + 1];
        float s = 0.f;
        for (int k = b; k < e; ++k) {
            int nb = csr[k];
            s += Xin[(size_t)nb * 64 + lane];
        }
        y -= H * ((float)(e - b) * x - s);
        x += H * y;
        Y[(size_t)v * 64 + lane] = y;
        Xout[(size_t)v * 64 + lane] = x;
    }

    // ---- oscillator layer, layer-major over this wave's node span ----
    // zprev_base is derived from Xout or Z (same restrict bases), so the
    // RAW deps (layer0 reads Xout written above; layer1 reads Z0 written
    // by layer0) are respected by alias analysis and same-thread ordering.
    auto do_layer = [&](int j, const float* zprev_base) {
        float wrow[64];
        const float* wp = Bw + ((size_t)j * 64 + lane) * 64;
#pragma unroll
        for (int q = 0; q < 16; ++q) {
            float4v w = *(const float4v*)(wp + 4 * q);
            wrow[4 * q + 0] = w[0]; wrow[4 * q + 1] = w[1];
            wrow[4 * q + 2] = w[2]; wrow[4 * q + 3] = w[3];
        }
        const float aj = osc_a[j * 64 + lane];
        const float bj = Bb[j * 64 + lane];
        float* Zj = Z + (size_t)j * nd;
        float* Uj = U + (size_t)j * nd;
        for (int v = v0; v < v1; ++v) {
            float zp = zprev_base[(size_t)v * 64 + lane];   // lane = d
            float z = Zj[(size_t)v * 64 + lane];
            float u = Uj[(size_t)v * 64 + lane];
            float acc = fmaf(aj, z, bj);
#pragma unroll
            for (int d = 0; d < 64; ++d)
                acc = fmaf(bcast_lane(zp, d), wrow[d], acc);
            float t = acc > 0.f ? acc : 0.f;
            u += H * t;
            z += H * u;
            Zj[(size_t)v * 64 + lane] = z;
            Uj[(size_t)v * 64 + lane] = u;
        }
    };

    do_layer(0, Xout);            // z_prev = X (new)
    do_layer(3, Z + 2 * nd);      // z_prev = Z2 (old)
    do_layer(2, Z + 1 * nd);      // z_prev = Z1 (old)
    do_layer(1, Z + 0 * nd);      // z_prev = Z0 (new, written by do_layer(0))
}

// ---------------- final: out[r][o] = sum_d Z3[root[r]][d] * fw[o][d] --------
__global__ void __launch_bounds__(256) final_kernel(
    const float* __restrict__ Z3, const int* __restrict__ roots,
    const float* __restrict__ fw, float* __restrict__ out, int R, int nout)
{
    int lane = threadIdx.x & 63;
    int r = (blockIdx.x * blockDim.x + threadIdx.x) >> 6;
    if (r >= R) return;
    int v = roots[r];
    float z = Z3[(size_t)v * 64 + lane];
    for (int o = 0; o < nout; ++o) {
        float w = fw[o * 64 + lane];
        float p = z * w;
#pragma unroll
        for (int off = 32; off > 0; off >>= 1)
            p += __shfl_xor(p, off);
        if (lane == 0) out[r * nout + o] = p;
    }
}

extern "C" void kernel_launch(void* const* d_in, const int* in_sizes, int n_in,
                              void* d_out, int out_size, void* d_ws, size_t ws_size,
                              hipStream_t stream)
{
    const int*   xnode   = (const int*)d_in[0];
    const int*   edge    = (const int*)d_in[1];
    const int*   roots   = (const int*)d_in[2];
    const float* key_emb = (const float*)d_in[3];
    const float* val_emb = (const float*)d_in[4];
    const float* lw      = (const float*)d_in[5];
    const float* lb      = (const float*)d_in[6];
    const float* osc_a   = (const float*)d_in[7];
    const float* Bw      = (const float*)d_in[8];
    const float* Bb      = (const float*)d_in[9];
    const float* fw      = (const float*)d_in[10];

    const int n = in_sizes[0] / 2;
    const int E = in_sizes[1] / 2;
    const int R = in_sizes[2];
    const int nout = out_size / R;
    const int* erow = edge;
    const int* ecol = edge + E;

    const size_t nd = (size_t)n * 64;
    float* X0buf   = (float*)d_ws;          // nd
    float* X1buf   = X0buf + nd;            // nd
    float* Y       = X1buf + nd;            // nd
    float* Z       = Y + nd;                // 4*nd
    float* U       = Z + 4 * nd;            // 4*nd
    int*   cnt     = (int*)(U + 4 * nd);    // n
    int*   ptr     = cnt + n;               // n+1
    int*   fillpos = ptr + n + 1;           // n
    int*   csr     = fillpos + n;           // E

    // zero Y,Z,U (contiguous, 9*nd floats) and degree counters
    hipMemsetAsync(Y, 0, 9 * nd * sizeof(float), stream);
    hipMemsetAsync(cnt, 0, (size_t)n * sizeof(int), stream);

    init_kernel<<<((size_t)n * 64 + 255) / 256, 256, 0, stream>>>(
        xnode, key_emb, val_emb, lw, lb, X0buf, n);
    count_kernel<<<(E + 255) / 256, 256, 0, stream>>>(ecol, cnt, E);
    scan_kernel<<<1, 1024, 0, stream>>>(cnt, ptr, fillpos, n);
    fill_kernel<<<(E + 255) / 256, 256, 0, stream>>>(erow, ecol, fillpos, csr, E);

    const int NPER = 13;                    // nodes per wave
    int nwaves  = (n + NPER - 1) / NPER;
    int nblocks = (nwaves + 3) / 4;         // 4 waves / 256-thread block
    float* xin = X0buf;
    float* xout = X1buf;
    for (int s = 0; s < 8; ++s) {
        step_kernel<<<nblocks, 256, 0, stream>>>(
            xin, xout, Y, Z, U, ptr, csr, osc_a, Bw, Bb, n, NPER);
        float* t = xin; xin = xout; xout = t;
    }

    final_kernel<<<((size_t)R * 64 + 255) / 256, 256, 0, stream>>>(
        Z + 3 * nd, roots, fw, (float*)d_out, R, nout);
}

// Round 2
// 521.444 us; speedup vs baseline: 3.4682x; 3.4682x over previous
//
#include <hip/hip_runtime.h>

#define H 0.1f

typedef float float4v __attribute__((ext_vector_type(4)));

__device__ __forceinline__ float bcast_lane(float v, int l) {
    return __int_as_float(__builtin_amdgcn_readlane(__float_as_int(v), l));
}

// ---------------- init: X0 = relu(W*(key_emb[x0]+val_emb[x1]) + b) ----------
__global__ void __launch_bounds__(256) init_kernel(
    const int* __restrict__ xnode, const float* __restrict__ key_emb,
    const float* __restrict__ val_emb, const float* __restrict__ lw,
    const float* __restrict__ lb, float* __restrict__ X0, int n)
{
    int lane = threadIdx.x & 63;
    int v = (blockIdx.x * blockDim.x + threadIdx.x) >> 6;
    if (v >= n) return;
    int k0 = xnode[2 * v + 0], k1 = xnode[2 * v + 1];
    float e = key_emb[k0 * 64 + lane] + val_emb[k1 * 64 + lane];
    float wrow[64];
    const float* wp = lw + (size_t)lane * 64;
#pragma unroll
    for (int q = 0; q < 16; ++q) {
        float4v w = *(const float4v*)(wp + 4 * q);
        wrow[4 * q + 0] = w[0]; wrow[4 * q + 1] = w[1];
        wrow[4 * q + 2] = w[2]; wrow[4 * q + 3] = w[3];
    }
    float acc = lb[lane];
#pragma unroll
    for (int d = 0; d < 64; ++d)
        acc = fmaf(bcast_lane(e, d), wrow[d], acc);
    X0[(size_t)v * 64 + lane] = acc > 0.f ? acc : 0.f;
}

// ---------------- CSR build ----------------
__global__ void __launch_bounds__(256) count_kernel(
    const int* __restrict__ col, int* __restrict__ cnt, int E)
{
    int e = blockIdx.x * blockDim.x + threadIdx.x;
    if (e < E) atomicAdd(&cnt[col[e]], 1);
}

__global__ void __launch_bounds__(1024) scan_kernel(
    const int* __restrict__ cnt, int* __restrict__ ptr,
    int* __restrict__ fillpos, int n)
{
    __shared__ int wsum[16];
    __shared__ int carry_s;
    int tid = threadIdx.x, lane = tid & 63, wid = tid >> 6;
    if (tid == 0) carry_s = 0;
    __syncthreads();
    for (int base = 0; base < n; base += 1024) {
        int i = base + tid;
        int v = (i < n) ? cnt[i] : 0;
        int s = v;
#pragma unroll
        for (int off = 1; off < 64; off <<= 1) {
            int t = __shfl_up(s, off);
            if (lane >= off) s += t;
        }
        if (lane == 63) wsum[wid] = s;
        __syncthreads();
        if (tid < 16) {
            int ws = wsum[tid];
#pragma unroll
            for (int off = 1; off < 16; off <<= 1) {
                int t = __shfl_up(ws, off);
                if (tid >= off) ws += t;
            }
            wsum[tid] = ws;
        }
        __syncthreads();
        int carry = carry_s;
        int wbase = (wid == 0) ? 0 : wsum[wid - 1];
        int excl = carry + wbase + (s - v);
        if (i < n) { ptr[i] = excl; fillpos[i] = excl; }
        __syncthreads();
        if (tid == 0) carry_s = carry + wsum[15];
        __syncthreads();
    }
    if (threadIdx.x == 0) ptr[n] = carry_s;
}

__global__ void __launch_bounds__(256) fill_kernel(
    const int* __restrict__ row, const int* __restrict__ col,
    int* __restrict__ fillpos, int* __restrict__ csr, int E)
{
    int e = blockIdx.x * blockDim.x + threadIdx.x;
    if (e < E) {
        int p = atomicAdd(&fillpos[col[e]], 1);
        csr[p] = row[e];
    }
}

// ---------------- wave layer: one leapfrog step over the graph -------------
// Xout = Xin + H*Ynew ; Ynew = Y - H*(deg*Xin - sum_nbr Xin[nbr])
__global__ void __launch_bounds__(256) wave_step(
    const float* __restrict__ Xin, float* __restrict__ Xout,
    float* __restrict__ Y, const int* __restrict__ ptr,
    const int* __restrict__ csr, int n)
{
    const int lane = threadIdx.x & 63;
    const int v = (blockIdx.x * blockDim.x + threadIdx.x) >> 6;
    if (v >= n) return;
    const size_t base = (size_t)v * 64 + lane;
    float x = Xin[base];
    float y = Y[base];
    int b = __builtin_amdgcn_readfirstlane(ptr[v]);
    int e = __builtin_amdgcn_readfirstlane(ptr[v + 1]);
    float s0 = 0.f, s1 = 0.f, s2 = 0.f, s3 = 0.f;
    int k = b;
    for (; k + 4 <= e; k += 4) {
        int n0 = csr[k], n1 = csr[k + 1], n2 = csr[k + 2], n3 = csr[k + 3];
        s0 += Xin[(size_t)n0 * 64 + lane];
        s1 += Xin[(size_t)n1 * 64 + lane];
        s2 += Xin[(size_t)n2 * 64 + lane];
        s3 += Xin[(size_t)n3 * 64 + lane];
    }
    for (; k < e; ++k) s0 += Xin[(size_t)csr[k] * 64 + lane];
    float s = (s0 + s1) + (s2 + s3);
    y -= H * ((float)(e - b) * x - s);
    x += H * y;
    Y[base] = y;
    Xout[base] = x;
}

// ---------------- oscillator stack for the ROOT nodes only -----------------
// Z,U for non-root nodes are dead code: the wave layer never reads them and
// the output uses only Z[3][roots]. 1024 roots x 8 steps x 4 layers.
__global__ void __launch_bounds__(256) root_osc(
    const float* __restrict__ Xall,   // [9][n][64]; Xall[s] = X after step s
    const int* __restrict__ roots, const float* __restrict__ osc_a,
    const float* __restrict__ Bw, const float* __restrict__ Bb,
    float* __restrict__ Z3out, int n, int R)
{
    const int lane = threadIdx.x & 63;
    const int r = (blockIdx.x * blockDim.x + threadIdx.x) >> 6;
    if (r >= R) return;
    const int v = roots[r];

    float z0 = 0.f, z1 = 0.f, z2 = 0.f, z3 = 0.f;
    float u0 = 0.f, u1 = 0.f, u2 = 0.f, u3 = 0.f;
    const float a0 = osc_a[0 * 64 + lane], a1 = osc_a[1 * 64 + lane];
    const float a2 = osc_a[2 * 64 + lane], a3 = osc_a[3 * 64 + lane];
    const float b0 = Bb[0 * 64 + lane], b1 = Bb[1 * 64 + lane];
    const float b2 = Bb[2 * 64 + lane], b3 = Bb[3 * 64 + lane];

    // u_new = u + H*relu(a*z + W @ zprev + b); z_new = z + H*u_new
    // sequential accumulator chain on purpose: matches R1's measured 4.7e-10.
    auto layer = [&](float& zj, float& uj, float zprev_vec, float aj, float bj,
                     const float* __restrict__ W) {
        float wrow[64];
        const float* wp = W + (size_t)lane * 64;
#pragma unroll
        for (int q = 0; q < 16; ++q) {
            float4v w = *(const float4v*)(wp + 4 * q);
            wrow[4 * q + 0] = w[0]; wrow[4 * q + 1] = w[1];
            wrow[4 * q + 2] = w[2]; wrow[4 * q + 3] = w[3];
        }
        float acc = fmaf(aj, zj, bj);
#pragma unroll
        for (int d = 0; d < 64; ++d)
            acc = fmaf(bcast_lane(zprev_vec, d), wrow[d], acc);
        float t = acc > 0.f ? acc : 0.f;
        uj += H * t;
        zj += H * uj;
    };

    for (int s = 1; s <= 8; ++s) {
        float xp = Xall[((size_t)s * n + v) * 64 + lane];
        layer(z0, u0, xp, a0, b0, Bw + 0 * 4096);   // layer0: zprev = X (new)
        layer(z3, u3, z2, a3, b3, Bw + 3 * 4096);   // layer3: zprev = Z2 (old)
        layer(z2, u2, z1, a2, b2, Bw + 2 * 4096);   // layer2: zprev = Z1 (old)
        layer(z1, u1, z0, a1, b1, Bw + 1 * 4096);   // layer1: zprev = Z0 (new)
    }
    Z3out[(size_t)r * 64 + lane] = z3;
}

// ---------------- final: out[r][o] = sum_d Z3[r][d] * fw[o][d] --------------
__global__ void __launch_bounds__(256) final_kernel(
    const float* __restrict__ Z3, const float* __restrict__ fw,
    float* __restrict__ out, int R, int nout)
{
    int lane = threadIdx.x & 63;
    int r = (blockIdx.x * blockDim.x + threadIdx.x) >> 6;
    if (r >= R) return;
    float z = Z3[(size_t)r * 64 + lane];
    for (int o = 0; o < nout; ++o) {
        float w = fw[o * 64 + lane];
        float p = z * w;
#pragma unroll
        for (int off = 32; off > 0; off >>= 1)
            p += __shfl_xor(p, off);
        if (lane == 0) out[r * nout + o] = p;
    }
}

extern "C" void kernel_launch(void* const* d_in, const int* in_sizes, int n_in,
                              void* d_out, int out_size, void* d_ws, size_t ws_size,
                              hipStream_t stream)
{
    const int*   xnode   = (const int*)d_in[0];
    const int*   edge    = (const int*)d_in[1];
    const int*   roots   = (const int*)d_in[2];
    const float* key_emb = (const float*)d_in[3];
    const float* val_emb = (const float*)d_in[4];
    const float* lw      = (const float*)d_in[5];
    const float* lb      = (const float*)d_in[6];
    const float* osc_a   = (const float*)d_in[7];
    const float* Bw      = (const float*)d_in[8];
    const float* Bb      = (const float*)d_in[9];
    const float* fw      = (const float*)d_in[10];

    const int n = in_sizes[0] / 2;
    const int E = in_sizes[1] / 2;
    const int R = in_sizes[2];
    const int nout = out_size / R;
    const int* erow = edge;
    const int* ecol = edge + E;

    const size_t nd = (size_t)n * 64;
    float* Xall    = (float*)d_ws;           // 9*nd  (X after step s, s=0..8)
    float* Y       = Xall + 9 * nd;          // nd
    float* Z3buf   = Y + nd;                 // R*64
    int*   cnt     = (int*)(Z3buf + (size_t)R * 64);  // n
    int*   ptr     = cnt + n;                // n+1
    int*   fillpos = ptr + n + 1;            // n
    int*   csr     = fillpos + n;            // E

    hipMemsetAsync(Y, 0, nd * sizeof(float), stream);
    hipMemsetAsync(cnt, 0, (size_t)n * sizeof(int), stream);

    init_kernel<<<((size_t)n * 64 + 255) / 256, 256, 0, stream>>>(
        xnode, key_emb, val_emb, lw, lb, Xall, n);
    count_kernel<<<(E + 255) / 256, 256, 0, stream>>>(ecol, cnt, E);
    scan_kernel<<<1, 1024, 0, stream>>>(cnt, ptr, fillpos, n);
    fill_kernel<<<(E + 255) / 256, 256, 0, stream>>>(erow, ecol, fillpos, csr, E);

    int nblocks = (n + 3) / 4;               // 4 waves (nodes) per 256-thread block
    for (int s = 0; s < 8; ++s) {
        wave_step<<<nblocks, 256, 0, stream>>>(
            Xall + (size_t)s * nd, Xall + (size_t)(s + 1) * nd, Y, ptr, csr, n);
    }

    root_osc<<<(R + 3) / 4, 256, 0, stream>>>(
        Xall, roots, osc_a, Bw, Bb, Z3buf, n, R);
    final_kernel<<<(R + 3) / 4, 256, 0, stream>>>(
        Z3buf, fw, (float*)d_out, R, nout);
}

// Round 3
// 467.231 us; speedup vs baseline: 3.8706x; 1.1160x over previous
//
#include <hip/hip_runtime.h>

#define H 0.1f

typedef float float4v __attribute__((ext_vector_type(4)));

__device__ __forceinline__ float bcast_lane(float v, int l) {
    return __int_as_float(__builtin_amdgcn_readlane(__float_as_int(v), l));
}

// ---------------- init: X0 = relu(W*(key_emb[x0]+val_emb[x1]) + b) ----------
// 4 nodes per wave: W row (64 f32) loaded once into regs, 4 uses per element,
// 4 independent FMA chains. lane = output dim o.
__global__ void __launch_bounds__(256) init_kernel(
    const int* __restrict__ xnode, const float* __restrict__ key_emb,
    const float* __restrict__ val_emb, const float* __restrict__ lw,
    const float* __restrict__ lb, float* __restrict__ X0, int n)
{
    const int lane = threadIdx.x & 63;
    const int w = (blockIdx.x * blockDim.x + threadIdx.x) >> 6;
    const int v0 = w * 4;
    if (v0 >= n) return;

    float4v wreg[16];
    const float* wp = lw + (size_t)lane * 64;
#pragma unroll
    for (int q = 0; q < 16; ++q) wreg[q] = *(const float4v*)(wp + 4 * q);
    const float bb = lb[lane];

    float e[4], acc[4];
#pragma unroll
    for (int g = 0; g < 4; ++g) {
        int v = v0 + g;
        if (v < n) {
            int k0 = xnode[2 * v + 0], k1 = xnode[2 * v + 1];
            e[g] = key_emb[k0 * 64 + lane] + val_emb[k1 * 64 + lane];
        } else e[g] = 0.f;
        acc[g] = bb;
    }
#pragma unroll
    for (int q = 0; q < 16; ++q)
#pragma unroll
        for (int j = 0; j < 4; ++j) {
            const int d = 4 * q + j;
#pragma unroll
            for (int g = 0; g < 4; ++g)
                acc[g] = fmaf(bcast_lane(e[g], d), wreg[q][j], acc[g]);
        }
#pragma unroll
    for (int g = 0; g < 4; ++g) {
        int v = v0 + g;
        if (v < n) X0[(size_t)v * 64 + lane] = acc[g] > 0.f ? acc[g] : 0.f;
    }
}

// ---------------- CSR build ----------------
__global__ void __launch_bounds__(256) count_kernel(
    const int* __restrict__ col, int* __restrict__ cnt, int E)
{
    int e = blockIdx.x * blockDim.x + threadIdx.x;
    if (e < E) atomicAdd(&cnt[col[e]], 1);
}

__global__ void __launch_bounds__(1024) scan_kernel(
    const int* __restrict__ cnt, int* __restrict__ ptr,
    int* __restrict__ fillpos, int n)
{
    __shared__ int wsum[16];
    __shared__ int carry_s;
    int tid = threadIdx.x, lane = tid & 63, wid = tid >> 6;
    if (tid == 0) carry_s = 0;
    __syncthreads();
    for (int base = 0; base < n; base += 1024) {
        int i = base + tid;
        int v = (i < n) ? cnt[i] : 0;
        int s = v;
#pragma unroll
        for (int off = 1; off < 64; off <<= 1) {
            int t = __shfl_up(s, off);
            if (lane >= off) s += t;
        }
        if (lane == 63) wsum[wid] = s;
        __syncthreads();
        if (tid < 16) {
            int ws = wsum[tid];
#pragma unroll
            for (int off = 1; off < 16; off <<= 1) {
                int t = __shfl_up(ws, off);
                if (tid >= off) ws += t;
            }
            wsum[tid] = ws;
        }
        __syncthreads();
        int carry = carry_s;
        int wbase = (wid == 0) ? 0 : wsum[wid - 1];
        int excl = carry + wbase + (s - v);
        if (i < n) { ptr[i] = excl; fillpos[i] = excl; }
        __syncthreads();
        if (tid == 0) carry_s = carry + wsum[15];
        __syncthreads();
    }
    if (threadIdx.x == 0) ptr[n] = carry_s;
}

__global__ void __launch_bounds__(256) fill_kernel(
    const int* __restrict__ row, const int* __restrict__ col,
    int* __restrict__ fillpos, int* __restrict__ csr, int E)
{
    int e = blockIdx.x * blockDim.x + threadIdx.x;
    if (e < E) {
        int p = atomicAdd(&fillpos[col[e]], 1);
        csr[p] = row[e];
    }
}

// ---------------- wave layer: one leapfrog step over the graph -------------
// 8 independent gather accumulators; csr indices issued ahead of gathers;
// Y is a single-use stream -> nontemporal; Xout is next step's gather target
// -> cached.
__global__ void __launch_bounds__(256) wave_step(
    const float* __restrict__ Xin, float* __restrict__ Xout,
    float* __restrict__ Y, const int* __restrict__ ptr,
    const int* __restrict__ csr, int n)
{
    const int lane = threadIdx.x & 63;
    const int v = (blockIdx.x * blockDim.x + threadIdx.x) >> 6;
    if (v >= n) return;
    const size_t base = (size_t)v * 64 + lane;
    int b = __builtin_amdgcn_readfirstlane(ptr[v]);
    int e = __builtin_amdgcn_readfirstlane(ptr[v + 1]);
    float x = Xin[base];
    float y = __builtin_nontemporal_load(&Y[base]);
    float s0 = 0.f, s1 = 0.f, s2 = 0.f, s3 = 0.f;
    float s4 = 0.f, s5 = 0.f, s6 = 0.f, s7 = 0.f;
    int k = b;
    for (; k + 8 <= e; k += 8) {
        int n0 = csr[k + 0], n1 = csr[k + 1], n2 = csr[k + 2], n3 = csr[k + 3];
        int n4 = csr[k + 4], n5 = csr[k + 5], n6 = csr[k + 6], n7 = csr[k + 7];
        s0 += Xin[(size_t)n0 * 64 + lane];
        s1 += Xin[(size_t)n1 * 64 + lane];
        s2 += Xin[(size_t)n2 * 64 + lane];
        s3 += Xin[(size_t)n3 * 64 + lane];
        s4 += Xin[(size_t)n4 * 64 + lane];
        s5 += Xin[(size_t)n5 * 64 + lane];
        s6 += Xin[(size_t)n6 * 64 + lane];
        s7 += Xin[(size_t)n7 * 64 + lane];
    }
    for (; k < e; ++k) s0 += Xin[(size_t)csr[k] * 64 + lane];
    float s = ((s0 + s1) + (s2 + s3)) + ((s4 + s5) + (s6 + s7));
    y -= H * ((float)(e - b) * x - s);
    x += H * y;
    __builtin_nontemporal_store(y, &Y[base]);
    Xout[base] = x;
}

// ---------------- oscillator stack for the ROOT nodes only -----------------
// Layer-cascade: each layer's full 8-step recurrence runs as one pass with
// its W row register-resident; the 8-step z-history lives in registers.
// Dataflow identical to the torch loop: z0^s<-X^s, z1^s<-z0^s (new),
// z2^s<-z1^{s-1} (old), z3^s<-z2^{s-1} (old).
__global__ void __launch_bounds__(64) root_osc(
    const float* __restrict__ Xall,   // [9][n][64]; Xall[s] = X after step s
    const int* __restrict__ roots, const float* __restrict__ osc_a,
    const float* __restrict__ Bw, const float* __restrict__ Bb,
    float* __restrict__ Z3out, int n, int R)
{
    const int lane = threadIdx.x;     // 0..63 = output dim o
    const int r = blockIdx.x;
    if (r >= R) return;
    const int v = roots[r];

    float hin[9], hout[9];

    // ---- pass 0: layer 0, zprev = X^s (from memory), same-step ----
    {
        float4v wreg[16];
        const float* wp = Bw + (size_t)lane * 64;
#pragma unroll
        for (int q = 0; q < 16; ++q) wreg[q] = *(const float4v*)(wp + 4 * q);
        const float aj = osc_a[lane];
        const float bj = Bb[lane];
        float z = 0.f, u = 0.f;
#pragma unroll
        for (int s = 1; s <= 8; ++s) {
            float zp = Xall[((size_t)s * n + v) * 64 + lane];
            float acc = fmaf(aj, z, bj);
#pragma unroll
            for (int q = 0; q < 16; ++q)
#pragma unroll
                for (int j = 0; j < 4; ++j)
                    acc = fmaf(bcast_lane(zp, 4 * q + j), wreg[q][j], acc);
            float t = acc > 0.f ? acc : 0.f;
            u += H * t;
            z += H * u;
            hout[s] = z;
        }
    }

    // ---- passes 1..3 ----
    auto pass = [&](int j, int prev_step) {
        float4v wreg[16];
        const float* wp = Bw + (size_t)j * 4096 + (size_t)lane * 64;
#pragma unroll
        for (int q = 0; q < 16; ++q) wreg[q] = *(const float4v*)(wp + 4 * q);
        const float aj = osc_a[j * 64 + lane];
        const float bj = Bb[j * 64 + lane];
        float z = 0.f, u = 0.f;
#pragma unroll
        for (int s = 1; s <= 8; ++s) {
            // both indices compile-time; runtime select only
            float zp = prev_step ? hin[s - 1] : hin[s];
            float acc = fmaf(aj, z, bj);
#pragma unroll
            for (int q = 0; q < 16; ++q)
#pragma unroll
                for (int jj = 0; jj < 4; ++jj)
                    acc = fmaf(bcast_lane(zp, 4 * q + jj), wreg[q][jj], acc);
            float t = acc > 0.f ? acc : 0.f;
            u += H * t;
            z += H * u;
            hout[s] = z;
        }
    };

    hin[0] = 0.f;
#pragma unroll
    for (int i = 1; i <= 8; ++i) hin[i] = hout[i];
    pass(1, 0);                     // layer1: zprev = z0^s (same step)
    hin[0] = 0.f;
#pragma unroll
    for (int i = 1; i <= 8; ++i) hin[i] = hout[i];
    pass(2, 1);                     // layer2: zprev = z1^{s-1}
    hin[0] = 0.f;
#pragma unroll
    for (int i = 1; i <= 8; ++i) hin[i] = hout[i];
    pass(3, 1);                     // layer3: zprev = z2^{s-1}

    Z3out[(size_t)r * 64 + lane] = hout[8];
}

// ---------------- final: out[r][o] = sum_d Z3[r][d] * fw[o][d] --------------
__global__ void __launch_bounds__(256) final_kernel(
    const float* __restrict__ Z3, const float* __restrict__ fw,
    float* __restrict__ out, int R, int nout)
{
    int lane = threadIdx.x & 63;
    int r = (blockIdx.x * blockDim.x + threadIdx.x) >> 6;
    if (r >= R) return;
    float z = Z3[(size_t)r * 64 + lane];
    for (int o = 0; o < nout; ++o) {
        float w = fw[o * 64 + lane];
        float p = z * w;
#pragma unroll
        for (int off = 32; off > 0; off >>= 1)
            p += __shfl_xor(p, off);
        if (lane == 0) out[r * nout + o] = p;
    }
}

extern "C" void kernel_launch(void* const* d_in, const int* in_sizes, int n_in,
                              void* d_out, int out_size, void* d_ws, size_t ws_size,
                              hipStream_t stream)
{
    const int*   xnode   = (const int*)d_in[0];
    const int*   edge    = (const int*)d_in[1];
    const int*   roots   = (const int*)d_in[2];
    const float* key_emb = (const float*)d_in[3];
    const float* val_emb = (const float*)d_in[4];
    const float* lw      = (const float*)d_in[5];
    const float* lb      = (const float*)d_in[6];
    const float* osc_a   = (const float*)d_in[7];
    const float* Bw      = (const float*)d_in[8];
    const float* Bb      = (const float*)d_in[9];
    const float* fw      = (const float*)d_in[10];

    const int n = in_sizes[0] / 2;
    const int E = in_sizes[1] / 2;
    const int R = in_sizes[2];
    const int nout = out_size / R;
    const int* erow = edge;
    const int* ecol = edge + E;

    const size_t nd = (size_t)n * 64;
    float* Xall    = (float*)d_ws;           // 9*nd  (X after step s, s=0..8)
    float* Y       = Xall + 9 * nd;          // nd
    float* Z3buf   = Y + nd;                 // R*64
    int*   cnt     = (int*)(Z3buf + (size_t)R * 64);  // n
    int*   ptr     = cnt + n;                // n+1
    int*   fillpos = ptr + n + 1;            // n
    int*   csr     = fillpos + n;            // E

    hipMemsetAsync(Y, 0, nd * sizeof(float), stream);
    hipMemsetAsync(cnt, 0, (size_t)n * sizeof(int), stream);

    {
        int waves = (n + 3) / 4;
        int blocks = (waves * 64 + 255) / 256;
        init_kernel<<<blocks, 256, 0, stream>>>(
            xnode, key_emb, val_emb, lw, lb, Xall, n);
    }
    count_kernel<<<(E + 255) / 256, 256, 0, stream>>>(ecol, cnt, E);
    scan_kernel<<<1, 1024, 0, stream>>>(cnt, ptr, fillpos, n);
    fill_kernel<<<(E + 255) / 256, 256, 0, stream>>>(erow, ecol, fillpos, csr, E);

    int nblocks = (n + 3) / 4;               // 4 waves (nodes) per 256-thread block
    for (int s = 0; s < 8; ++s) {
        wave_step<<<nblocks, 256, 0, stream>>>(
            Xall + (size_t)s * nd, Xall + (size_t)(s + 1) * nd, Y, ptr, csr, n);
    }

    root_osc<<<R, 64, 0, stream>>>(
        Xall, roots, osc_a, Bw, Bb, Z3buf, n, R);
    final_kernel<<<(R + 3) / 4, 256, 0, stream>>>(
        Z3buf, fw, (float*)d_out, R, nout);
}

// Round 4
// 318.565 us; speedup vs baseline: 5.6769x; 1.4667x over previous
//
#include <hip/hip_runtime.h>

#define H 0.1f

typedef float float4v __attribute__((ext_vector_type(4)));

__device__ __forceinline__ float bcast_lane(float v, int l) {
    return __int_as_float(__builtin_amdgcn_readlane(__float_as_int(v), l));
}

// ---------------- init: X0 = relu(W*(key_emb[x0]+val_emb[x1]) + b) ----------
// 4 nodes per wave: W row (64 f32) register-resident, 4 uses per element.
__global__ void __launch_bounds__(256) init_kernel(
    const int* __restrict__ xnode, const float* __restrict__ key_emb,
    const float* __restrict__ val_emb, const float* __restrict__ lw,
    const float* __restrict__ lb, float* __restrict__ X0, int n)
{
    const int lane = threadIdx.x & 63;
    const int w = (blockIdx.x * blockDim.x + threadIdx.x) >> 6;
    const int v0 = w * 4;
    if (v0 >= n) return;

    float4v wreg[16];
    const float* wp = lw + (size_t)lane * 64;
#pragma unroll
    for (int q = 0; q < 16; ++q) wreg[q] = *(const float4v*)(wp + 4 * q);
    const float bb = lb[lane];

    float e[4], acc[4];
#pragma unroll
    for (int g = 0; g < 4; ++g) {
        int v = v0 + g;
        if (v < n) {
            int k0 = xnode[2 * v + 0], k1 = xnode[2 * v + 1];
            e[g] = key_emb[k0 * 64 + lane] + val_emb[k1 * 64 + lane];
        } else e[g] = 0.f;
        acc[g] = bb;
    }
#pragma unroll
    for (int q = 0; q < 16; ++q)
#pragma unroll
        for (int j = 0; j < 4; ++j) {
            const int d = 4 * q + j;
#pragma unroll
            for (int g = 0; g < 4; ++g)
                acc[g] = fmaf(bcast_lane(e[g], d), wreg[q][j], acc[g]);
        }
#pragma unroll
    for (int g = 0; g < 4; ++g) {
        int v = v0 + g;
        if (v < n) X0[(size_t)v * 64 + lane] = acc[g] > 0.f ? acc[g] : 0.f;
    }
}

// ---------------- CSR ptr from the SORTED edge row array -------------------
// np.unique(e, axis=1) sorts columns lexicographically -> erow is ascending.
// Symmetric edge list => row-CSR aggregation == col segment_sum, and the
// adjacency array is simply ecol in place. ptr[v] = first e with erow[e] >= v.
__global__ void __launch_bounds__(256) bounds_kernel(
    const int* __restrict__ erow, int* __restrict__ ptr, int n, int E)
{
    int e = blockIdx.x * blockDim.x + threadIdx.x;
    if (e >= E) return;
    int b = erow[e];
    int a = (e == 0) ? -1 : erow[e - 1];
    for (int v = a + 1; v <= b; ++v) ptr[v] = e;
    if (e == E - 1)
        for (int v = b + 1; v <= n; ++v) ptr[v] = E;
}

// ---------------- wave layer: one leapfrog step over the graph -------------
__global__ void __launch_bounds__(256) wave_step(
    const float* __restrict__ Xin, float* __restrict__ Xout,
    float* __restrict__ Y, const int* __restrict__ ptr,
    const int* __restrict__ csr, int n)
{
    const int lane = threadIdx.x & 63;
    const int v = (blockIdx.x * blockDim.x + threadIdx.x) >> 6;
    if (v >= n) return;
    const size_t base = (size_t)v * 64 + lane;
    int b = __builtin_amdgcn_readfirstlane(ptr[v]);
    int e = __builtin_amdgcn_readfirstlane(ptr[v + 1]);
    float x = Xin[base];
    float y = __builtin_nontemporal_load(&Y[base]);
    float s0 = 0.f, s1 = 0.f, s2 = 0.f, s3 = 0.f;
    float s4 = 0.f, s5 = 0.f, s6 = 0.f, s7 = 0.f;
    int k = b;
    for (; k + 8 <= e; k += 8) {
        int n0 = csr[k + 0], n1 = csr[k + 1], n2 = csr[k + 2], n3 = csr[k + 3];
        int n4 = csr[k + 4], n5 = csr[k + 5], n6 = csr[k + 6], n7 = csr[k + 7];
        s0 += Xin[(size_t)n0 * 64 + lane];
        s1 += Xin[(size_t)n1 * 64 + lane];
        s2 += Xin[(size_t)n2 * 64 + lane];
        s3 += Xin[(size_t)n3 * 64 + lane];
        s4 += Xin[(size_t)n4 * 64 + lane];
        s5 += Xin[(size_t)n5 * 64 + lane];
        s6 += Xin[(size_t)n6 * 64 + lane];
        s7 += Xin[(size_t)n7 * 64 + lane];
    }
    if (k + 4 <= e) {
        int n0 = csr[k + 0], n1 = csr[k + 1], n2 = csr[k + 2], n3 = csr[k + 3];
        s0 += Xin[(size_t)n0 * 64 + lane];
        s1 += Xin[(size_t)n1 * 64 + lane];
        s2 += Xin[(size_t)n2 * 64 + lane];
        s3 += Xin[(size_t)n3 * 64 + lane];
        k += 4;
    }
    for (; k < e; ++k) s0 += Xin[(size_t)csr[k] * 64 + lane];
    float s = ((s0 + s1) + (s2 + s3)) + ((s4 + s5) + (s6 + s7));
    y -= H * ((float)(e - b) * x - s);
    x += H * y;
    __builtin_nontemporal_store(y, &Y[base]);
    Xout[base] = x;
}

// ---------------- oscillator stack for the ROOT nodes only -----------------
// Layer-cascade: each layer's full 8-step recurrence in one pass, W row
// register-resident, 8-step z-history in registers (compile-time indexed).
__global__ void __launch_bounds__(64) root_osc(
    const float* __restrict__ Xall,   // [9][n][64]; Xall[s] = X after step s
    const int* __restrict__ roots, const float* __restrict__ osc_a,
    const float* __restrict__ Bw, const float* __restrict__ Bb,
    float* __restrict__ Z3out, int n, int R)
{
    const int lane = threadIdx.x;     // 0..63 = output dim o
    const int r = blockIdx.x;
    if (r >= R) return;
    const int v = roots[r];

    float hin[9], hout[9];

    // ---- pass 0: layer 0, zprev = X^s (same step, from memory) ----
    {
        float4v wreg[16];
        const float* wp = Bw + (size_t)lane * 64;
#pragma unroll
        for (int q = 0; q < 16; ++q) wreg[q] = *(const float4v*)(wp + 4 * q);
        const float aj = osc_a[lane];
        const float bj = Bb[lane];
        float z = 0.f, u = 0.f;
#pragma unroll
        for (int s = 1; s <= 8; ++s) {
            float zp = Xall[((size_t)s * n + v) * 64 + lane];
            float acc = fmaf(aj, z, bj);
#pragma unroll
            for (int q = 0; q < 16; ++q)
#pragma unroll
                for (int j = 0; j < 4; ++j)
                    acc = fmaf(bcast_lane(zp, 4 * q + j), wreg[q][j], acc);
            float t = acc > 0.f ? acc : 0.f;
            u += H * t;
            z += H * u;
            hout[s] = z;
        }
    }

    auto pass = [&](int j, int prev_step) {
        float4v wreg[16];
        const float* wp = Bw + (size_t)j * 4096 + (size_t)lane * 64;
#pragma unroll
        for (int q = 0; q < 16; ++q) wreg[q] = *(const float4v*)(wp + 4 * q);
        const float aj = osc_a[j * 64 + lane];
        const float bj = Bb[j * 64 + lane];
        float z = 0.f, u = 0.f;
#pragma unroll
        for (int s = 1; s <= 8; ++s) {
            float zp = prev_step ? hin[s - 1] : hin[s];
            float acc = fmaf(aj, z, bj);
#pragma unroll
            for (int q = 0; q < 16; ++q)
#pragma unroll
                for (int jj = 0; jj < 4; ++jj)
                    acc = fmaf(bcast_lane(zp, 4 * q + jj), wreg[q][jj], acc);
            float t = acc > 0.f ? acc : 0.f;
            u += H * t;
            z += H * u;
            hout[s] = z;
        }
    };

    hin[0] = 0.f;
#pragma unroll
    for (int i = 1; i <= 8; ++i) hin[i] = hout[i];
    pass(1, 0);                     // layer1: zprev = z0^s (same step)
    hin[0] = 0.f;
#pragma unroll
    for (int i = 1; i <= 8; ++i) hin[i] = hout[i];
    pass(2, 1);                     // layer2: zprev = z1^{s-1}
    hin[0] = 0.f;
#pragma unroll
    for (int i = 1; i <= 8; ++i) hin[i] = hout[i];
    pass(3, 1);                     // layer3: zprev = z2^{s-1}

    Z3out[(size_t)r * 64 + lane] = hout[8];
}

// ---------------- final: out[r][o] = sum_d Z3[r][d] * fw[o][d] --------------
__global__ void __launch_bounds__(256) final_kernel(
    const float* __restrict__ Z3, const float* __restrict__ fw,
    float* __restrict__ out, int R, int nout)
{
    int lane = threadIdx.x & 63;
    int r = (blockIdx.x * blockDim.x + threadIdx.x) >> 6;
    if (r >= R) return;
    float z = Z3[(size_t)r * 64 + lane];
    for (int o = 0; o < nout; ++o) {
        float w = fw[o * 64 + lane];
        float p = z * w;
#pragma unroll
        for (int off = 32; off > 0; off >>= 1)
            p += __shfl_xor(p, off);
        if (lane == 0) out[r * nout + o] = p;
    }
}

extern "C" void kernel_launch(void* const* d_in, const int* in_sizes, int n_in,
                              void* d_out, int out_size, void* d_ws, size_t ws_size,
                              hipStream_t stream)
{
    const int*   xnode   = (const int*)d_in[0];
    const int*   edge    = (const int*)d_in[1];
    const int*   roots   = (const int*)d_in[2];
    const float* key_emb = (const float*)d_in[3];
    const float* val_emb = (const float*)d_in[4];
    const float* lw      = (const float*)d_in[5];
    const float* lb      = (const float*)d_in[6];
    const float* osc_a   = (const float*)d_in[7];
    const float* Bw      = (const float*)d_in[8];
    const float* Bb      = (const float*)d_in[9];
    const float* fw      = (const float*)d_in[10];

    const int n = in_sizes[0] / 2;
    const int E = in_sizes[1] / 2;
    const int R = in_sizes[2];
    const int nout = out_size / R;
    const int* erow = edge;       // sorted ascending (np.unique axis=1)
    const int* ecol = edge + E;   // adjacency array of the row-CSR, in place

    const size_t nd = (size_t)n * 64;
    float* Xall  = (float*)d_ws;                     // 9*nd
    float* Y     = Xall + 9 * nd;                    // nd
    float* Z3buf = Y + nd;                           // R*64
    int*   ptr   = (int*)(Z3buf + (size_t)R * 64);   // n+1

    hipMemsetAsync(Y, 0, nd * sizeof(float), stream);

    {
        int waves = (n + 3) / 4;
        int blocks = (waves * 64 + 255) / 256;
        init_kernel<<<blocks, 256, 0, stream>>>(
            xnode, key_emb, val_emb, lw, lb, Xall, n);
    }
    bounds_kernel<<<(E + 255) / 256, 256, 0, stream>>>(erow, ptr, n, E);

    int nblocks = (n + 3) / 4;    // 4 waves (nodes) per 256-thread block
    for (int s = 0; s < 8; ++s) {
        wave_step<<<nblocks, 256, 0, stream>>>(
            Xall + (size_t)s * nd, Xall + (size_t)(s + 1) * nd, Y, ptr, ecol, n);
    }

    root_osc<<<R, 64, 0, stream>>>(
        Xall, roots, osc_a, Bw, Bb, Z3buf, n, R);
    final_kernel<<<(R + 3) / 4, 256, 0, stream>>>(
        Z3buf, fw, (float*)d_out, R, nout);
}

// Round 5
// 272.490 us; speedup vs baseline: 6.6369x; 1.1691x over previous
//
#include <hip/hip_runtime.h>

#define H 0.1f

typedef float float4v __attribute__((ext_vector_type(4)));

__device__ __forceinline__ float bcast_lane(float v, int l) {
    return __int_as_float(__builtin_amdgcn_readlane(__float_as_int(v), l));
}

// ---- table: Wk[k][o] = sum_d key_emb[k][d]*W[o][d] + b[o];  Wv likewise ----
// One wave per (table, k) pair. lane = o.
__global__ void __launch_bounds__(64) table_kernel(
    const float* __restrict__ key_emb, const float* __restrict__ val_emb,
    const float* __restrict__ lw, const float* __restrict__ lb,
    float* __restrict__ Wk, float* __restrict__ Wv, int K)
{
    const int lane = threadIdx.x;
    const int which = blockIdx.x >= K;        // 0 = key, 1 = val
    const int k = which ? blockIdx.x - K : blockIdx.x;

    float4v wreg[16];
    const float* wp = lw + (size_t)lane * 64;
#pragma unroll
    for (int q = 0; q < 16; ++q) wreg[q] = *(const float4v*)(wp + 4 * q);

    const float* emb = which ? val_emb : key_emb;
    float e = emb[k * 64 + lane];
    float acc = which ? 0.f : lb[lane];
#pragma unroll
    for (int q = 0; q < 16; ++q)
#pragma unroll
        for (int j = 0; j < 4; ++j)
            acc = fmaf(bcast_lane(e, 4 * q + j), wreg[q][j], acc);
    (which ? Wv : Wk)[k * 64 + lane] = acc;
}

// ---- init: X0[v][o] = relu(Wk[k0[v]][o] + Wv[k1[v]][o]) --------------------
__global__ void __launch_bounds__(256) init2_kernel(
    const int* __restrict__ xnode, const float* __restrict__ Wk,
    const float* __restrict__ Wv, float* __restrict__ X0, int n)
{
    const int lane = threadIdx.x & 63;
    const int v = (blockIdx.x * blockDim.x + threadIdx.x) >> 6;
    if (v >= n) return;
    int k0 = __builtin_amdgcn_readfirstlane(xnode[2 * v + 0]);
    int k1 = __builtin_amdgcn_readfirstlane(xnode[2 * v + 1]);
    float p = Wk[k0 * 64 + lane] + Wv[k1 * 64 + lane];
    X0[(size_t)v * 64 + lane] = p > 0.f ? p : 0.f;
}

// ---- CSR ptr from the SORTED edge row array --------------------------------
// np.unique(e, axis=1) sorts columns lexicographically -> erow ascending;
// symmetric edge list => adjacency array is ecol in place.
__global__ void __launch_bounds__(256) bounds_kernel(
    const int* __restrict__ erow, int* __restrict__ ptr, int n, int E)
{
    int e = blockIdx.x * blockDim.x + threadIdx.x;
    if (e >= E) return;
    int b = erow[e];
    int a = (e == 0) ? -1 : erow[e - 1];
    for (int v = a + 1; v <= b; ++v) ptr[v] = e;
    if (e == E - 1)
        for (int v = b + 1; v <= n; ++v) ptr[v] = E;
}

// ---- wave layer, 3-term form: X_{s+1} = 2X_s - X_{s-1} - H^2*Lap(X_s) ------
// (Y eliminated: with Y0=0, H*Y_s = X_s - X_{s-1}.)
__global__ void __launch_bounds__(256) wave_step(
    const float* __restrict__ Xin, const float* __restrict__ Xm1,
    float* __restrict__ Xout, const int* __restrict__ ptr,
    const int* __restrict__ csr, int n)
{
    const int lane = threadIdx.x & 63;
    const int v = (blockIdx.x * blockDim.x + threadIdx.x) >> 6;
    if (v >= n) return;
    const size_t base = (size_t)v * 64 + lane;
    int b = __builtin_amdgcn_readfirstlane(ptr[v]);
    int e = __builtin_amdgcn_readfirstlane(ptr[v + 1]);
    float x = Xin[base];
    float xm1 = __builtin_nontemporal_load(&Xm1[base]);   // single-use stream
    float s0 = 0.f, s1 = 0.f, s2 = 0.f, s3 = 0.f;
    float s4 = 0.f, s5 = 0.f, s6 = 0.f, s7 = 0.f;
    int k = b;
    for (; k + 8 <= e; k += 8) {
        int n0 = csr[k + 0], n1 = csr[k + 1], n2 = csr[k + 2], n3 = csr[k + 3];
        int n4 = csr[k + 4], n5 = csr[k + 5], n6 = csr[k + 6], n7 = csr[k + 7];
        s0 += Xin[(size_t)n0 * 64 + lane];
        s1 += Xin[(size_t)n1 * 64 + lane];
        s2 += Xin[(size_t)n2 * 64 + lane];
        s3 += Xin[(size_t)n3 * 64 + lane];
        s4 += Xin[(size_t)n4 * 64 + lane];
        s5 += Xin[(size_t)n5 * 64 + lane];
        s6 += Xin[(size_t)n6 * 64 + lane];
        s7 += Xin[(size_t)n7 * 64 + lane];
    }
    if (k + 4 <= e) {
        int n0 = csr[k + 0], n1 = csr[k + 1], n2 = csr[k + 2], n3 = csr[k + 3];
        s0 += Xin[(size_t)n0 * 64 + lane];
        s1 += Xin[(size_t)n1 * 64 + lane];
        s2 += Xin[(size_t)n2 * 64 + lane];
        s3 += Xin[(size_t)n3 * 64 + lane];
        k += 4;
    }
    for (; k < e; ++k) s0 += Xin[(size_t)csr[k] * 64 + lane];
    float s = ((s0 + s1) + (s2 + s3)) + ((s4 + s5) + (s6 + s7));
    float lap = fmaf((float)(e - b), x, -s);
    float xn = fmaf(-(H * H), lap, (x + x) - xm1);
    Xout[base] = xn;
}

// ---- oscillator stack for the ROOT nodes only ------------------------------
__global__ void __launch_bounds__(64) root_osc(
    const float* __restrict__ Xall,   // [9][n][64]
    const int* __restrict__ roots, const float* __restrict__ osc_a,
    const float* __restrict__ Bw, const float* __restrict__ Bb,
    float* __restrict__ Z3out, int n, int R)
{
    const int lane = threadIdx.x;
    const int r = blockIdx.x;
    if (r >= R) return;
    const int v = roots[r];

    float hin[9], hout[9];

    {   // pass 0: layer 0, zprev = X^s (same step, from memory)
        float4v wreg[16];
        const float* wp = Bw + (size_t)lane * 64;
#pragma unroll
        for (int q = 0; q < 16; ++q) wreg[q] = *(const float4v*)(wp + 4 * q);
        const float aj = osc_a[lane];
        const float bj = Bb[lane];
        float z = 0.f, u = 0.f;
#pragma unroll
        for (int s = 1; s <= 8; ++s) {
            float zp = Xall[((size_t)s * n + v) * 64 + lane];
            float acc = fmaf(aj, z, bj);
#pragma unroll
            for (int q = 0; q < 16; ++q)
#pragma unroll
                for (int j = 0; j < 4; ++j)
                    acc = fmaf(bcast_lane(zp, 4 * q + j), wreg[q][j], acc);
            float t = acc > 0.f ? acc : 0.f;
            u += H * t;
            z += H * u;
            hout[s] = z;
        }
    }

    auto pass = [&](int j, int prev_step) {
        float4v wreg[16];
        const float* wp = Bw + (size_t)j * 4096 + (size_t)lane * 64;
#pragma unroll
        for (int q = 0; q < 16; ++q) wreg[q] = *(const float4v*)(wp + 4 * q);
        const float aj = osc_a[j * 64 + lane];
        const float bj = Bb[j * 64 + lane];
        float z = 0.f, u = 0.f;
#pragma unroll
        for (int s = 1; s <= 8; ++s) {
            float zp = prev_step ? hin[s - 1] : hin[s];
            float acc = fmaf(aj, z, bj);
#pragma unroll
            for (int q = 0; q < 16; ++q)
#pragma unroll
                for (int jj = 0; jj < 4; ++jj)
                    acc = fmaf(bcast_lane(zp, 4 * q + jj), wreg[q][jj], acc);
            float t = acc > 0.f ? acc : 0.f;
            u += H * t;
            z += H * u;
            hout[s] = z;
        }
    };

    hin[0] = 0.f;
#pragma unroll
    for (int i = 1; i <= 8; ++i) hin[i] = hout[i];
    pass(1, 0);                     // layer1: zprev = z0^s (same step)
    hin[0] = 0.f;
#pragma unroll
    for (int i = 1; i <= 8; ++i) hin[i] = hout[i];
    pass(2, 1);                     // layer2: zprev = z1^{s-1}
    hin[0] = 0.f;
#pragma unroll
    for (int i = 1; i <= 8; ++i) hin[i] = hout[i];
    pass(3, 1);                     // layer3: zprev = z2^{s-1}

    Z3out[(size_t)r * 64 + lane] = hout[8];
}

// ---- final: out[r][o] = sum_d Z3[r][d] * fw[o][d] ---------------------------
__global__ void __launch_bounds__(256) final_kernel(
    const float* __restrict__ Z3, const float* __restrict__ fw,
    float* __restrict__ out, int R, int nout)
{
    int lane = threadIdx.x & 63;
    int r = (blockIdx.x * blockDim.x + threadIdx.x) >> 6;
    if (r >= R) return;
    float z = Z3[(size_t)r * 64 + lane];
    for (int o = 0; o < nout; ++o) {
        float w = fw[o * 64 + lane];
        float p = z * w;
#pragma unroll
        for (int off = 32; off > 0; off >>= 1)
            p += __shfl_xor(p, off);
        if (lane == 0) out[r * nout + o] = p;
    }
}

extern "C" void kernel_launch(void* const* d_in, const int* in_sizes, int n_in,
                              void* d_out, int out_size, void* d_ws, size_t ws_size,
                              hipStream_t stream)
{
    const int*   xnode   = (const int*)d_in[0];
    const int*   edge    = (const int*)d_in[1];
    const int*   roots   = (const int*)d_in[2];
    const float* key_emb = (const float*)d_in[3];
    const float* val_emb = (const float*)d_in[4];
    const float* lw      = (const float*)d_in[5];
    const float* lb      = (const float*)d_in[6];
    const float* osc_a   = (const float*)d_in[7];
    const float* Bw      = (const float*)d_in[8];
    const float* Bb      = (const float*)d_in[9];
    const float* fw      = (const float*)d_in[10];

    const int n = in_sizes[0] / 2;
    const int E = in_sizes[1] / 2;
    const int R = in_sizes[2];
    const int K = in_sizes[3] / 64;   // rows of key_emb (= input_dim+1)
    const int nout = out_size / R;
    const int* erow = edge;           // sorted ascending (np.unique axis=1)
    const int* ecol = edge + E;       // adjacency array of the row-CSR, in place

    const size_t nd = (size_t)n * 64;
    float* Xall  = (float*)d_ws;                     // 9*nd
    float* Z3buf = Xall + 9 * nd;                    // R*64
    float* Wk    = Z3buf + (size_t)R * 64;           // K*64
    float* Wv    = Wk + (size_t)K * 64;              // K*64
    int*   ptr   = (int*)(Wv + (size_t)K * 64);      // n+1

    table_kernel<<<2 * K, 64, 0, stream>>>(key_emb, val_emb, lw, lb, Wk, Wv, K);
    bounds_kernel<<<(E + 255) / 256, 256, 0, stream>>>(erow, ptr, n, E);
    init2_kernel<<<(n * 64 + 255) / 256, 256, 0, stream>>>(xnode, Wk, Wv, Xall, n);

    int nblocks = (n + 3) / 4;        // 4 waves (nodes) per 256-thread block
    for (int s = 0; s < 8; ++s) {
        const float* xin = Xall + (size_t)s * nd;
        const float* xm1 = (s == 0) ? xin : Xall + (size_t)(s - 1) * nd;
        wave_step<<<nblocks, 256, 0, stream>>>(
            xin, xm1, Xall + (size_t)(s + 1) * nd, ptr, ecol, n);
    }

    root_osc<<<R, 64, 0, stream>>>(
        Xall, roots, osc_a, Bw, Bb, Z3buf, n, R);
    final_kernel<<<(R + 3) / 4, 256, 0, stream>>>(
        Z3buf, fw, (float*)d_out, R, nout);
}

// Round 6
// 246.833 us; speedup vs baseline: 7.3267x; 1.1039x over previous
//
#include <hip/hip_runtime.h>

#define H 0.1f

typedef float float4v __attribute__((ext_vector_type(4)));

__device__ __forceinline__ float bcast_lane(float v, int l) {
    return __int_as_float(__builtin_amdgcn_readlane(__float_as_int(v), l));
}

// ---- table: Wk[k][o] = sum_d key_emb[k][d]*W[o][d] + b[o];  Wv likewise ----
__global__ void __launch_bounds__(64) table_kernel(
    const float* __restrict__ key_emb, const float* __restrict__ val_emb,
    const float* __restrict__ lw, const float* __restrict__ lb,
    float* __restrict__ Wk, float* __restrict__ Wv, int K)
{
    const int lane = threadIdx.x;
    const int which = blockIdx.x >= K;        // 0 = key, 1 = val
    const int k = which ? blockIdx.x - K : blockIdx.x;

    float4v wreg[16];
    const float* wp = lw + (size_t)lane * 64;
#pragma unroll
    for (int q = 0; q < 16; ++q) wreg[q] = *(const float4v*)(wp + 4 * q);

    const float* emb = which ? val_emb : key_emb;
    float e = emb[k * 64 + lane];
    float acc = which ? 0.f : lb[lane];
#pragma unroll
    for (int q = 0; q < 16; ++q)
#pragma unroll
        for (int j = 0; j < 4; ++j)
            acc = fmaf(bcast_lane(e, 4 * q + j), wreg[q][j], acc);
    (which ? Wv : Wk)[k * 64 + lane] = acc;
}

// ---- init: X0[v][o] = relu(Wk[k0[v]][o] + Wv[k1[v]][o]) --------------------
__global__ void __launch_bounds__(256) init2_kernel(
    const int* __restrict__ xnode, const float* __restrict__ Wk,
    const float* __restrict__ Wv, float* __restrict__ X0, int n)
{
    const int lane = threadIdx.x & 63;
    const int v = (blockIdx.x * blockDim.x + threadIdx.x) >> 6;
    if (v >= n) return;
    unsigned k0 = (unsigned)__builtin_amdgcn_readfirstlane(xnode[2 * v + 0]);
    unsigned k1 = (unsigned)__builtin_amdgcn_readfirstlane(xnode[2 * v + 1]);
    float p = Wk[(k0 << 6) + lane] + Wv[(k1 << 6) + lane];
    X0[((unsigned)v << 6) + lane] = p > 0.f ? p : 0.f;
}

// ---- CSR ptr from the SORTED edge row array --------------------------------
// np.unique(e, axis=1) sorts columns lexicographically -> erow ascending;
// symmetric edge list => adjacency array is ecol in place.
__global__ void __launch_bounds__(256) bounds_kernel(
    const int* __restrict__ erow, int* __restrict__ ptr, int n, int E)
{
    int e = blockIdx.x * blockDim.x + threadIdx.x;
    if (e >= E) return;
    int b = erow[e];
    int a = (e == 0) ? -1 : erow[e - 1];
    for (int v = a + 1; v <= b; ++v) ptr[v] = e;
    if (e == E - 1)
        for (int v = b + 1; v <= n; ++v) ptr[v] = E;
}

// ---- gather body shared by wave_step / root_wave ---------------------------
// 32-bit element offsets: SGPR-base + u32 voffset addressing, 1 VALU/gather.
__device__ __forceinline__ float wave_update(
    const float* __restrict__ Xin, float x, float xm1, int lane, int b, int e,
    const int* __restrict__ csr)
{
    const float* Xl = Xin + lane;
    float s0 = 0.f, s1 = 0.f, s2 = 0.f, s3 = 0.f;
    float s4 = 0.f, s5 = 0.f, s6 = 0.f, s7 = 0.f;
    int k = b;
    for (; k + 8 <= e; k += 8) {
        unsigned n0 = (unsigned)csr[k + 0], n1 = (unsigned)csr[k + 1];
        unsigned n2 = (unsigned)csr[k + 2], n3 = (unsigned)csr[k + 3];
        unsigned n4 = (unsigned)csr[k + 4], n5 = (unsigned)csr[k + 5];
        unsigned n6 = (unsigned)csr[k + 6], n7 = (unsigned)csr[k + 7];
        s0 += Xl[n0 << 6];
        s1 += Xl[n1 << 6];
        s2 += Xl[n2 << 6];
        s3 += Xl[n3 << 6];
        s4 += Xl[n4 << 6];
        s5 += Xl[n5 << 6];
        s6 += Xl[n6 << 6];
        s7 += Xl[n7 << 6];
    }
    if (k + 4 <= e) {
        unsigned n0 = (unsigned)csr[k + 0], n1 = (unsigned)csr[k + 1];
        unsigned n2 = (unsigned)csr[k + 2], n3 = (unsigned)csr[k + 3];
        s0 += Xl[n0 << 6];
        s1 += Xl[n1 << 6];
        s2 += Xl[n2 << 6];
        s3 += Xl[n3 << 6];
        k += 4;
    }
    for (; k < e; ++k) s0 += Xl[(unsigned)csr[k] << 6];
    float s = ((s0 + s1) + (s2 + s3)) + ((s4 + s5) + (s6 + s7));
    float lap = fmaf((float)(e - b), x, -s);
    return fmaf(-(H * H), lap, (x + x) - xm1);
}

// ---- wave layer, 3-term form: X_{s+1} = 2X_s - X_{s-1} - H^2*Lap(X_s) ------
__global__ void __launch_bounds__(256) wave_step(
    const float* __restrict__ Xin, const float* __restrict__ Xm1,
    float* __restrict__ Xout, const int* __restrict__ ptr,
    const int* __restrict__ csr, int n)
{
    const int lane = threadIdx.x & 63;
    const int v = (blockIdx.x * blockDim.x + threadIdx.x) >> 6;
    if (v >= n) return;
    const unsigned base = ((unsigned)v << 6) + lane;
    int b = __builtin_amdgcn_readfirstlane(ptr[v]);
    int e = __builtin_amdgcn_readfirstlane(ptr[v + 1]);
    float x = Xin[base];
    float xm1 = __builtin_nontemporal_load(&Xm1[base]);   // single-use stream
    Xout[base] = wave_update(Xin, x, xm1, lane, b, e, csr);
}

// ---- last wave step, restricted to the root nodes --------------------------
// X_8 is consumed only by root_osc at the roots; never a gather source.
__global__ void __launch_bounds__(256) root_wave(
    const float* __restrict__ Xin, const float* __restrict__ Xm1,
    const int* __restrict__ roots, float* __restrict__ X8r,
    const int* __restrict__ ptr, const int* __restrict__ csr, int R)
{
    const int lane = threadIdx.x & 63;
    const int r = (blockIdx.x * blockDim.x + threadIdx.x) >> 6;
    if (r >= R) return;
    const int v = __builtin_amdgcn_readfirstlane(roots[r]);
    const unsigned base = ((unsigned)v << 6) + lane;
    int b = __builtin_amdgcn_readfirstlane(ptr[v]);
    int e = __builtin_amdgcn_readfirstlane(ptr[v + 1]);
    float x = Xin[base];
    float xm1 = Xm1[base];
    X8r[((unsigned)r << 6) + lane] = wave_update(Xin, x, xm1, lane, b, e, csr);
}

// ---- oscillator stack for the ROOT nodes only ------------------------------
__global__ void __launch_bounds__(64) root_osc(
    const float* __restrict__ Xall,   // [8][n][64], planes 0..7
    const float* __restrict__ X8r,    // [R][64], plane 8 at roots
    const int* __restrict__ roots, const float* __restrict__ osc_a,
    const float* __restrict__ Bw, const float* __restrict__ Bb,
    float* __restrict__ Z3out, int n, int R)
{
    const int lane = threadIdx.x;
    const int r = blockIdx.x;
    if (r >= R) return;
    const int v = roots[r];

    float hin[9], hout[9];

    {   // pass 0: layer 0, zprev = X^s (same step, from memory)
        float4v wreg[16];
        const float* wp = Bw + (size_t)lane * 64;
#pragma unroll
        for (int q = 0; q < 16; ++q) wreg[q] = *(const float4v*)(wp + 4 * q);
        const float aj = osc_a[lane];
        const float bj = Bb[lane];
        float z = 0.f, u = 0.f;
#pragma unroll
        for (int s = 1; s <= 8; ++s) {
            float zp = (s < 8) ? Xall[((size_t)s * n + v) * 64 + lane]
                               : X8r[((unsigned)r << 6) + lane];
            float acc = fmaf(aj, z, bj);
#pragma unroll
            for (int q = 0; q < 16; ++q)
#pragma unroll
                for (int j = 0; j < 4; ++j)
                    acc = fmaf(bcast_lane(zp, 4 * q + j), wreg[q][j], acc);
            float t = acc > 0.f ? acc : 0.f;
            u += H * t;
            z += H * u;
            hout[s] = z;
        }
    }

    auto pass = [&](int j, int prev_step) {
        float4v wreg[16];
        const float* wp = Bw + (size_t)j * 4096 + (size_t)lane * 64;
#pragma unroll
        for (int q = 0; q < 16; ++q) wreg[q] = *(const float4v*)(wp + 4 * q);
        const float aj = osc_a[j * 64 + lane];
        const float bj = Bb[j * 64 + lane];
        float z = 0.f, u = 0.f;
#pragma unroll
        for (int s = 1; s <= 8; ++s) {
            float zp = prev_step ? hin[s - 1] : hin[s];
            float acc = fmaf(aj, z, bj);
#pragma unroll
            for (int q = 0; q < 16; ++q)
#pragma unroll
                for (int jj = 0; jj < 4; ++jj)
                    acc = fmaf(bcast_lane(zp, 4 * q + jj), wreg[q][jj], acc);
            float t = acc > 0.f ? acc : 0.f;
            u += H * t;
            z += H * u;
            hout[s] = z;
        }
    };

    hin[0] = 0.f;
#pragma unroll
    for (int i = 1; i <= 8; ++i) hin[i] = hout[i];
    pass(1, 0);                     // layer1: zprev = z0^s (same step)
    hin[0] = 0.f;
#pragma unroll
    for (int i = 1; i <= 8; ++i) hin[i] = hout[i];
    pass(2, 1);                     // layer2: zprev = z1^{s-1}
    hin[0] = 0.f;
#pragma unroll
    for (int i = 1; i <= 8; ++i) hin[i] = hout[i];
    pass(3, 1);                     // layer3: zprev = z2^{s-1}

    Z3out[((unsigned)r << 6) + lane] = hout[8];
}

// ---- final: out[r][o] = sum_d Z3[r][d] * fw[o][d] ---------------------------
__global__ void __launch_bounds__(256) final_kernel(
    const float* __restrict__ Z3, const float* __restrict__ fw,
    float* __restrict__ out, int R, int nout)
{
    int lane = threadIdx.x & 63;
    int r = (blockIdx.x * blockDim.x + threadIdx.x) >> 6;
    if (r >= R) return;
    float z = Z3[((unsigned)r << 6) + lane];
    for (int o = 0; o < nout; ++o) {
        float w = fw[o * 64 + lane];
        float p = z * w;
#pragma unroll
        for (int off = 32; off > 0; off >>= 1)
            p += __shfl_xor(p, off);
        if (lane == 0) out[r * nout + o] = p;
    }
}

extern "C" void kernel_launch(void* const* d_in, const int* in_sizes, int n_in,
                              void* d_out, int out_size, void* d_ws, size_t ws_size,
                              hipStream_t stream)
{
    const int*   xnode   = (const int*)d_in[0];
    const int*   edge    = (const int*)d_in[1];
    const int*   roots   = (const int*)d_in[2];
    const float* key_emb = (const float*)d_in[3];
    const float* val_emb = (const float*)d_in[4];
    const float* lw      = (const float*)d_in[5];
    const float* lb      = (const float*)d_in[6];
    const float* osc_a   = (const float*)d_in[7];
    const float* Bw      = (const float*)d_in[8];
    const float* Bb      = (const float*)d_in[9];
    const float* fw      = (const float*)d_in[10];

    const int n = in_sizes[0] / 2;
    const int E = in_sizes[1] / 2;
    const int R = in_sizes[2];
    const int K = in_sizes[3] / 64;   // rows of key_emb (= input_dim+1)
    const int nout = out_size / R;
    const int* erow = edge;           // sorted ascending (np.unique axis=1)
    const int* ecol = edge + E;       // adjacency array of the row-CSR, in place

    const size_t nd = (size_t)n * 64;
    float* Xall  = (float*)d_ws;                     // 8*nd (planes 0..7)
    float* X8r   = Xall + 8 * nd;                    // R*64
    float* Z3buf = X8r + (size_t)R * 64;             // R*64
    float* Wk    = Z3buf + (size_t)R * 64;           // K*64
    float* Wv    = Wk + (size_t)K * 64;              // K*64
    int*   ptr   = (int*)(Wv + (size_t)K * 64);      // n+1

    table_kernel<<<2 * K, 64, 0, stream>>>(key_emb, val_emb, lw, lb, Wk, Wv, K);
    bounds_kernel<<<(E + 255) / 256, 256, 0, stream>>>(erow, ptr, n, E);
    init2_kernel<<<(n * 64 + 255) / 256, 256, 0, stream>>>(xnode, Wk, Wv, Xall, n);

    int nblocks = (n + 3) / 4;        // 4 waves (nodes) per 256-thread block
    for (int s = 0; s < 7; ++s) {     // full steps produce planes 1..7
        const float* xin = Xall + (size_t)s * nd;
        const float* xm1 = (s == 0) ? xin : Xall + (size_t)(s - 1) * nd;
        wave_step<<<nblocks, 256, 0, stream>>>(
            xin, xm1, Xall + (size_t)(s + 1) * nd, ptr, ecol, n);
    }
    // 8th step only at roots (X_8 is never a gather source)
    root_wave<<<(R + 3) / 4, 256, 0, stream>>>(
        Xall + 7 * nd, Xall + 6 * nd, roots, X8r, ptr, ecol, R);

    root_osc<<<R, 64, 0, stream>>>(
        Xall, X8r, roots, osc_a, Bw, Bb, Z3buf, n, R);
    final_kernel<<<(R + 3) / 4, 256, 0, stream>>>(
        Z3buf, fw, (float*)d_out, R, nout);
}